// Round 7
// baseline (153.839 us; speedup 1.0000x reference)
//
#include <hip/hip_runtime.h>
#include <hip/hip_bf16.h>
#include <math.h>

#define L1_     5248
#define LENRRC_ 129
#define TSTART_ 65
#define NWIN_   5120
#define SWZ(m) ((m) + ((m) >> 3))     // stride-8 reads -> stride-9 -> conflict-free

typedef __attribute__((ext_vector_type(8))) short s16x8;   // 8 bf16 lanes (4 VGPRs)
typedef __attribute__((ext_vector_type(4))) float f32x4;   // MFMA accumulator

__device__ inline ushort bf16_rne(float x) {
    unsigned xb = __float_as_uint(x);
    return (ushort)((xb + 0x7fffu + ((xb >> 16) & 1u)) >> 16);
}

__device__ inline float wave_sum(float v) {
    #pragma unroll
    for (int m = 32; m > 0; m >>= 1) v += __shfl_xor(v, m, 64);
    return v;
}
__device__ inline float wave_max(float v) {
    #pragma unroll
    for (int m = 32; m > 0; m >>= 1) v = fmaxf(v, __shfl_xor(v, m, 64));
    return v;
}

// direct global->LDS 16B staging (dest = wave-uniform base + lane*16)
__device__ inline void gl_lds16(const void* g, void* l) {
    __builtin_amdgcn_global_load_lds(
        (const __attribute__((address_space(1))) unsigned int*)g,
        (__attribute__((address_space(3))) unsigned int*)l, 16, 0, 0);
}

// ---------- pack: W1^T bf16 | W2^T bf16 | (fallback: z=bias) ----------
__global__ __launch_bounds__(256) void pack_k(const float* __restrict__ W1,
        const float* __restrict__ W2, const float* __restrict__ benc,
        ushort* __restrict__ w1t, ushort* __restrict__ w2t, float* __restrict__ z)
{
    __shared__ ushort tile[64][70];
    const int blk = blockIdx.x, tid = threadIdx.x;
    if (blk < 768) {                                   // transpose W1 / W2 into bf16
        const float* W; ushort* T; int K, N, n0, k0;
        if (blk < 384) {
            int idx = blk;                             // grid (8,48)
            W = W1; T = w1t; K = 3072; N = 512;
            n0 = (idx & 7) * 64; k0 = (idx >> 3) * 64;
        } else {
            int idx = blk - 384;                       // grid (48,8)
            W = W2; T = w2t; K = 512; N = 3072;
            n0 = (idx % 48) * 64; k0 = (idx / 48) * 64;
        }
        const int cr = tid >> 4, cc = (tid & 15) * 4;
        #pragma unroll
        for (int i = 0; i < 4; ++i) {
            int kk = i * 16 + cr;
            float4 v = *(const float4*)&W[(size_t)(k0 + kk) * N + n0 + cc];
            tile[kk][cc]     = bf16_rne(v.x);
            tile[kk][cc + 1] = bf16_rne(v.y);
            tile[kk][cc + 2] = bf16_rne(v.z);
            tile[kk][cc + 3] = bf16_rne(v.w);
        }
        __syncthreads();
        #pragma unroll
        for (int i = 0; i < 4; ++i) {
            int nn = i * 16 + cr;
            ushort4 h;
            h.x = tile[cc][nn]; h.y = tile[cc + 1][nn];
            h.z = tile[cc + 2][nn]; h.w = tile[cc + 3][nn];
            *(ushort4*)&T[(size_t)(n0 + nn) * K + k0 + cc] = h;
        }
    } else {                                           // fallback only: init z with bias
        int i = (blk - 768) * 256 + tid;               // 524288 total
        z[i] = benc[i & 511];
    }
}

// ---------- gemm1: A from f32 x (cvt in-flight), B gl_lds, SK=8 partial panels ----------
__global__ __launch_bounds__(256) void gemm1_k(const float* __restrict__ Ax,
        const ushort* __restrict__ Bb, float* __restrict__ C, int M, int N, int K,
        int partial)
{
    __shared__ __attribute__((aligned(16))) ushort Asl[64 * 64];    // 8 KB, linear
    __shared__ __attribute__((aligned(16))) ushort Bsl[128 * 64];   // 16 KB, linear
    const int tid = threadIdx.x;
    const int lane = tid & 63, wave = tid >> 6;
    const int wm = (wave >> 1) * 32, wn = (wave & 1) * 64;
    const int m0 = blockIdx.y * 64, n0 = blockIdx.x * 128;
    const int kch = K / 8, kbeg = blockIdx.z * kch, kend = kbeg + kch;
    const int fm = lane & 15, q = lane >> 4;
    f32x4 acc[2][4] = {};

    // per-lane staging coords: chunk c -> (row, kb) with kb inverse-swizzled,
    // so linear LDS dest holds the XOR-swizzled layout (rule 21: both-sides)
    int arow[2], akb[2], brow[4], bkb[4];
    #pragma unroll
    for (int j = 0; j < 2; ++j) {
        int c = ((wave * 2 + j) << 6) + lane;
        arow[j] = c >> 3; akb[j] = (c & 7) ^ (arow[j] & 7);
    }
    #pragma unroll
    for (int j = 0; j < 4; ++j) {
        int c = ((wave * 4 + j) << 6) + lane;
        brow[j] = c >> 3; bkb[j] = (c & 7) ^ (brow[j] & 7);
    }

    for (int kt = kbeg; kt < kend; kt += 64) {
        #pragma unroll
        for (int j = 0; j < 4; ++j)                    // B 128x64: DMA first (overlaps A cvt)
            gl_lds16(&Bb[(size_t)(n0 + brow[j]) * K + kt + bkb[j] * 8],
                     &Bsl[(wave * 4 + j) << 9]);
        #pragma unroll
        for (int j = 0; j < 2; ++j) {                  // A 64x64: f32 load -> bf16 -> ds_write
            int c = ((wave * 2 + j) << 6) + lane;
            const float* src = &Ax[(size_t)(m0 + arow[j]) * K + kt + akb[j] * 8];
            float4 v0 = *(const float4*)src;
            float4 v1 = *(const float4*)(src + 4);
            s16x8 hv;
            hv[0] = (short)bf16_rne(v0.x); hv[1] = (short)bf16_rne(v0.y);
            hv[2] = (short)bf16_rne(v0.z); hv[3] = (short)bf16_rne(v0.w);
            hv[4] = (short)bf16_rne(v1.x); hv[5] = (short)bf16_rne(v1.y);
            hv[6] = (short)bf16_rne(v1.z); hv[7] = (short)bf16_rne(v1.w);
            *(s16x8*)&Asl[c * 8] = hv;
        }
        __syncthreads();                               // vmcnt+lgkm drain inserted here
        #pragma unroll
        for (int ks = 0; ks < 2; ++ks) {
            s16x8 a[2], b[4];
            #pragma unroll
            for (int mf = 0; mf < 2; ++mf) {
                int r = wm + mf * 16 + fm;
                a[mf] = *(const s16x8*)&Asl[(r << 6) + ((((ks << 2) + q) ^ (r & 7)) << 3)];
            }
            #pragma unroll
            for (int nf = 0; nf < 4; ++nf) {
                int r = wn + nf * 16 + fm;
                b[nf] = *(const s16x8*)&Bsl[(r << 6) + ((((ks << 2) + q) ^ (r & 7)) << 3)];
            }
            #pragma unroll
            for (int mf = 0; mf < 2; ++mf)
                #pragma unroll
                for (int nf = 0; nf < 4; ++nf)
                    acc[mf][nf] = __builtin_amdgcn_mfma_f32_16x16x32_bf16(a[mf], b[nf], acc[mf][nf], 0, 0, 0);
        }
        __syncthreads();
    }

    if (partial) {                                     // deterministic per-split panel
        float* Cs = C + (size_t)blockIdx.z * ((size_t)M * N);
        #pragma unroll
        for (int mf = 0; mf < 2; ++mf)
            #pragma unroll
            for (int nf = 0; nf < 4; ++nf)
                #pragma unroll
                for (int r = 0; r < 4; ++r) {
                    int m = m0 + wm + mf * 16 + q * 4 + r;
                    int n = n0 + wn + nf * 16 + fm;
                    Cs[(size_t)m * N + n] = acc[mf][nf][r];
                }
    } else {                                           // fallback: atomic accumulate
        #pragma unroll
        for (int mf = 0; mf < 2; ++mf)
            #pragma unroll
            for (int nf = 0; nf < 4; ++nf)
                #pragma unroll
                for (int r = 0; r < 4; ++r) {
                    int m = m0 + wm + mf * 16 + q * 4 + r;
                    int n = n0 + wn + nf * 16 + fm;
                    atomicAdd(&C[(size_t)m * N + n], acc[mf][nf][r]);
                }
    }
}

// ---------- gemm2: 64x64xBK64, global_load_lds + XOR-swizzle, + bias, fused PAPR loss ----------
__global__ __launch_bounds__(256) void gemm2_k(const ushort* __restrict__ Ab,
        const ushort* __restrict__ Bb, const float* __restrict__ bias,
        const float* __restrict__ papr, float* __restrict__ C,
        float* __restrict__ out_loss, int M, int N, int K)
{
    __shared__ __attribute__((aligned(16))) ushort Asl[64 * 64];
    __shared__ __attribute__((aligned(16))) ushort Bsl[64 * 64];
    __shared__ float red[4];
    const int tid = threadIdx.x;
    const int lane = tid & 63, wave = tid >> 6;
    const int wm = (wave >> 1) * 32, wn = (wave & 1) * 32;
    const int m0 = blockIdx.y * 64, n0 = blockIdx.x * 64;
    const int fm = lane & 15, q = lane >> 4;
    f32x4 acc[2][2] = {};

    int srow[2], skb[2];
    #pragma unroll
    for (int j = 0; j < 2; ++j) {
        int c = ((wave * 2 + j) << 6) + lane;
        srow[j] = c >> 3; skb[j] = (c & 7) ^ (srow[j] & 7);
    }

    for (int kt = 0; kt < K; kt += 64) {
        #pragma unroll
        for (int j = 0; j < 2; ++j) {
            gl_lds16(&Ab[(size_t)(m0 + srow[j]) * K + kt + skb[j] * 8],
                     &Asl[(wave * 2 + j) << 9]);
            gl_lds16(&Bb[(size_t)(n0 + srow[j]) * K + kt + skb[j] * 8],
                     &Bsl[(wave * 2 + j) << 9]);
        }
        __syncthreads();
        #pragma unroll
        for (int ks = 0; ks < 2; ++ks) {
            s16x8 a[2], b[2];
            #pragma unroll
            for (int mf = 0; mf < 2; ++mf) {
                int r = wm + mf * 16 + fm;
                a[mf] = *(const s16x8*)&Asl[(r << 6) + ((((ks << 2) + q) ^ (r & 7)) << 3)];
            }
            #pragma unroll
            for (int nf = 0; nf < 2; ++nf) {
                int r = wn + nf * 16 + fm;
                b[nf] = *(const s16x8*)&Bsl[(r << 6) + ((((ks << 2) + q) ^ (r & 7)) << 3)];
            }
            #pragma unroll
            for (int mf = 0; mf < 2; ++mf)
                #pragma unroll
                for (int nf = 0; nf < 2; ++nf)
                    acc[mf][nf] = __builtin_amdgcn_mfma_f32_16x16x32_bf16(a[mf], b[nf], acc[mf][nf], 0, 0, 0);
        }
        __syncthreads();
    }

    #pragma unroll
    for (int mf = 0; mf < 2; ++mf)
        #pragma unroll
        for (int nf = 0; nf < 2; ++nf)
            #pragma unroll
            for (int r = 0; r < 4; ++r) {
                int m = m0 + wm + mf * 16 + q * 4 + r;
                int n = n0 + wn + nf * 16 + fm;
                C[(size_t)m * N + n] = acc[mf][nf][r] + bias[n];
            }

    if (blockIdx.x == 0 && blockIdx.y == 0) {          // fused PAPR loss
        float s = 0.f;
        for (int i = tid; i < 1024; i += 256) { float v = papr[i] - 8.f; s += v > 0.f ? v : 0.f; }
        s = wave_sum(s);
        if (lane == 0) red[wave] = s;
        __syncthreads();
        if (tid == 0) *out_loss = (red[0] + red[1] + red[2] + red[3]) * (1.f / 1024.f);
    }
}

// ---------- megakernel: 1024 threads, 2 rows/block, halved phase chains ----------
// P1+P2 == IDFT64(fftshift(DFT32(z))): with z~[q]=(-1)^q z[q],
//   d[2m]  = (1/sqrt2) * e^{2pi i 2m sloc/64} * z~[m]
//   d[odd n] = (1/sqrt2048) * e^{2pi i n sloc/64} * ( Sum z~ + i * Sum z~[q] cot(pi(n-2q)/64) )
// P7+P8 is the adjoint with identical structure on w~[n] = w[n] e^{-2pi i n sloc/64}.
__global__ __launch_bounds__(1024, 4) void mega_k(const float* __restrict__ z,
        const float* __restrict__ benc,
        const float* __restrict__ rrc, const float* __restrict__ awgn,
        const int* __restrict__ slocp, ushort* __restrict__ y5b,
        float* __restrict__ papr, float* __restrict__ out_papr, int nsp)
{
    __shared__ float  zl[2][512];
    __shared__ float2 trti[2][672];    // P12 out (CP layout) / reused as w~[s*64+n] after P6
    __shared__ float  hl[132];
    __shared__ float  csl[16], ssl[16];
    __shared__ float2 cs64[64];
    __shared__ float  ct[64];          // cot(pi*j/64), odd j only
    __shared__ __attribute__((aligned(16))) float2 gcs[130];
    __shared__ float  dxr[2][SWZ(L1_ - 1) + 1];
    __shared__ float  red[2][16], red2[2][16];

    const int b0 = blockIdx.x * 2, b1 = b0 + 1;
    const int tid = threadIdx.x;
    const int lane = tid & 63, wv = tid >> 6;          // wv 0..15
    const int sloc = *slocp;
    const float S2048 = 0.02209708691207961f;          // 1/sqrt(2048)

    // ---- tables ----
    if (tid < 64) {
        float ang = 0.09817477042468103f * (float)tid;   // 2pi/64
        float s, c; sincosf(ang, &s, &c);
        cs64[tid] = make_float2(c, s);
    }
    if (tid >= 64 && tid < 80) {
        int t = tid - 64;
        float ang = 1.9634954084936207f * (float)t;      // 2pi*5/16
        float s, c; sincosf(ang, &s, &c);
        csl[t] = 1.4142135623730951f * c; ssl[t] = 1.4142135623730951f * s;
    }
    if (tid >= 96 && tid < 160) {                        // trti zero pads, both rows
        int t = (tid - 96) & 31, row = (tid - 96) >> 5;
        int idx = (t < 16) ? t : (640 + t);              // [0..15] and [656..671]
        trti[row][idx] = make_float2(0.f, 0.f);
    }
    if (tid >= 160 && tid < 224) {                       // cot table (odd entries)
        int j = tid - 160;
        float v = 0.f;
        if (j & 1) { float s, c; sincosf(0.04908738521234052f * (float)j, &s, &c); v = c / s; }
        ct[j] = v;
    }
    if (tid >= 256 && tid < 256 + LENRRC_) hl[tid - 256] = rrc[tid - 256];

    // ---- z: one value per thread (threads 0..511 -> row0, 512..1023 -> row1) ----
    const int zrow = tid >> 9, zi = tid & 511;
    float va;
    if (nsp) {
        va = benc[zi];
        const float* zp = z + (size_t)(b0 + zrow) * 512;
        for (int s = 0; s < nsp; ++s)
            va += zp[(size_t)s * 524288 + zi];
    } else {
        va = z[(size_t)(b0 + zrow) * 512 + zi];
    }
    __syncthreads();

    // ---- gcs: carrier folded into RRC taps ----
    if (tid < LENRRC_) {
        int neg = (16 - (tid & 15)) & 15;                // (-d) & 15
        gcs[tid] = make_float2(hl[tid] * csl[neg], hl[tid] * ssl[neg]);
    }

    // ---- power norm (waves 0-7 = row0, 8-15 = row1); fold (-1)^q into zl ----
    {
        float S = wave_sum(va);
        float Q = wave_sum(va * va);
        if (lane == 0) { red[0][wv] = S; red2[0][wv] = Q; }
    }
    __syncthreads();
    {
        int rb = zrow * 8;
        float S = 0.f, Q = 0.f;
        #pragma unroll
        for (int w = 0; w < 8; ++w) { S += red[0][rb + w]; Q += red2[0][rb + w]; }
        float mean = S * (1.f / 512.f);
        float var = (Q - S * mean) * (1.f / 511.f);
        float inv = 1.f / (sqrtf(var) + 1e-8f);
        float sg = ((zi >> 1) & 1) ? -1.f : 1.f;         // (-1)^q, q = zi>>1
        zl[zrow][zi] = (va - mean) * inv * sg;
    }
    __syncthreads();

    // ---- P12: fused DFT32+IDFT64+CP, pair-split over q (16 iters + shfl) ----
    {
        int slot = tid >> 1, h = tid & 1;
        int r = slot >> 8, t = slot & 255;
        int s = t >> 5, j = t & 31;
        int base = s * 80;                               // data at [base+32 .. base+95]
        const float2* zs = (const float2*)&zl[r][s * 64];
        int n = 2 * j + 1;
        float Zr = 0.f, Zi = 0.f, Tr = 0.f, Ti = 0.f;
        int qb = 16 * h;
        #pragma unroll 4
        for (int q = qb; q < qb + 16; ++q) {
            float2 a = zs[q];
            float w = ct[(n - 2 * q) & 63];
            Zr += a.x; Zi += a.y;
            Tr += a.x * w; Ti += a.y * w;
        }
        Zr += __shfl_xor(Zr, 1, 64); Zi += __shfl_xor(Zi, 1, 64);
        Tr += __shfl_xor(Tr, 1, 64); Ti += __shfl_xor(Ti, 1, 64);
        if (h == 0) {
            {   // odd n = 2j+1
                float2 cw = cs64[(n * sloc) & 63];
                float Ar = Zr - Ti, Ai = Zi + Tr;        // Z + i*T
                float dr = S2048 * (Ar * cw.x - Ai * cw.y);
                float di = S2048 * (Ai * cw.x + Ar * cw.y);
                trti[r][base + 32 + n] = make_float2(dr, di);
                if (n >= 48) trti[r][base + n - 32] = make_float2(dr, di);   // CP
            }
            {   // even n = 2j: trivial (interpolation identity)
                int n2 = 2 * j;
                float2 a = zs[j];
                float2 cw = cs64[(n2 * sloc) & 63];
                const float RS2 = 0.7071067811865476f;   // 1/sqrt2
                float dr = RS2 * (a.x * cw.x - a.y * cw.y);
                float di = RS2 * (a.y * cw.x + a.x * cw.y);
                trti[r][base + 32 + n2] = make_float2(dr, di);
                if (n2 >= 48) trti[r][base + n2 - 32] = make_float2(dr, di); // CP
            }
        }
    }
    __syncthreads();

    // ---- P3: upsample x8 + RRC polyphase + carrier, task=(a,g), both rows share hl ----
    float ss0 = 0.f, ss1 = 0.f;
    for (int tsk = tid; tsk < 1312; tsk += 1024) {
        int a = tsk >> 1, g = tsk & 1;
        float ar0[4] = {}, ai0[4] = {}, ar1[4] = {}, ai1[4] = {};
        #pragma unroll 4
        for (int d = 0; d < 16; ++d) {
            float2 t0 = trti[0][16 + a - d];             // zero-padded: no bounds check
            float2 t1 = trti[1][16 + a - d];
            #pragma unroll
            for (int r = 0; r < 4; ++r) {
                float h = hl[g * 4 + r + 8 * d];
                ar0[r] += t0.x * h; ai0[r] += t0.y * h;
                ar1[r] += t1.x * h; ai1[r] += t1.y * h;
            }
        }
        if (g == 0) {                                    // d=16, tap 128, r=0 only
            float2 t0 = trti[0][a], t1 = trti[1][a];
            float h = hl[128];
            ar0[0] += t0.x * h; ai0[0] += t0.y * h;
            ar1[0] += t1.x * h; ai1[0] += t1.y * h;
        }
        int cb = (a & 1) * 8;
        #pragma unroll
        for (int r = 0; r < 4; ++r) {
            int rr = g * 4 + r;
            float cv = csl[cb + rr], sv = ssl[cb + rr];
            float v0 = ar0[r] * cv - ai0[r] * sv;
            float v1 = ar1[r] * cv - ai1[r] * sv;
            dxr[0][SWZ(a * 8 + rr)] = v0;
            dxr[1][SWZ(a * 8 + rr)] = v1;
            ss0 += v0 * v0; ss1 += v1 * v1;
        }
    }
    ss0 = wave_sum(ss0); ss1 = wave_sum(ss1);
    if (lane == 0) { red[0][wv] = ss0; red[1][wv] = ss1; }
    __syncthreads();
    float thr0, thr1;
    {
        float S0 = 0.f, S1 = 0.f;
        #pragma unroll
        for (int w = 0; w < 16; ++w) { S0 += red[0][w]; S1 += red[1][w]; }
        thr0 = 1.2f * sqrtf(S0 / (float)L1_);
        thr1 = 1.2f * sqrtf(S1 / (float)L1_);
    }
    __syncthreads();

    // ---- P5: clip + PAPR window stats + AWGN (in place), both rows ----
    float pm0 = 0.f, ps0 = 0.f, pm1 = 0.f, ps1 = 0.f;
    {
        const float4* ag0 = (const float4*)&awgn[(size_t)b0 * L1_];
        const float4* ag1 = (const float4*)&awgn[(size_t)b1 * L1_];
        for (int ii = tid; ii < 1312; ii += 1024) {      // 1312*4 = 5248
            float4 a0 = ag0[ii], a1 = ag1[ii];
            int i = ii * 4;
            #pragma unroll
            for (int e = 0; e < 4; ++e) {
                int idx = i + e;
                bool win = (idx >= TSTART_ && idx < TSTART_ + NWIN_);
                float aw0 = (e == 0) ? a0.x : (e == 1) ? a0.y : (e == 2) ? a0.z : a0.w;
                float aw1 = (e == 0) ? a1.x : (e == 1) ? a1.y : (e == 2) ? a1.z : a1.w;
                {
                    float x = dxr[0][SWZ(idx)];
                    float ax = fabsf(x);
                    float over = fmaxf(ax - thr0, 0.f);
                    float y = (1.f - over / (ax + 1e-8f)) * x;
                    if (win) { float p = y * y; ps0 += p; pm0 = fmaxf(pm0, p); }
                    dxr[0][SWZ(idx)] = y + aw0;
                }
                {
                    float x = dxr[1][SWZ(idx)];
                    float ax = fabsf(x);
                    float over = fmaxf(ax - thr1, 0.f);
                    float y = (1.f - over / (ax + 1e-8f)) * x;
                    if (win) { float p = y * y; ps1 += p; pm1 = fmaxf(pm1, p); }
                    dxr[1][SWZ(idx)] = y + aw1;
                }
            }
        }
    }
    ps0 = wave_sum(ps0); pm0 = wave_max(pm0);
    ps1 = wave_sum(ps1); pm1 = wave_max(pm1);
    if (lane == 0) { red[0][wv] = ps0; red2[0][wv] = pm0; red[1][wv] = ps1; red2[1][wv] = pm1; }
    __syncthreads();
    if (tid == 0) {
        float s0 = 0.f, m0 = 0.f, s1 = 0.f, m1 = 0.f;
        #pragma unroll
        for (int w = 0; w < 16; ++w) {
            s0 += red[0][w]; m0 = fmaxf(m0, red2[0][w]);
            s1 += red[1][w]; m1 = fmaxf(m1, red2[1][w]);
        }
        float p0 = 10.f * log10f(m0 / (s0 / (float)NWIN_));
        float p1 = 10.f * log10f(m1 / (s1 / (float)NWIN_));
        papr[b0] = p0; out_papr[b0] = p0;
        papr[b1] = p1; out_papr[b1] = p1;
    }
    __syncthreads();     // all P5 dxr writes visible before P6

    // ---- P6: matched RRC filter, 1 output/thread -> w~ = w*conj(W[n*sloc]) ----
    {
        int r = tid >> 9, o = tid & 511;                 // row, output slot
        int s = o >> 6, n = o & 63;
        int T0 = s * 80 + n + 32;                        // Nf/8
        int base = 9 * T0;                               // SWZ(Nf)
        float ar = 0.f, ai = 0.f;
        int db = 0;
        #pragma unroll 4
        for (int e = 0; e < 16; ++e) {
            float4 g01 = *(const float4*)&gcs[db];       // gcs[db], gcs[db+1]
            float4 g23 = *(const float4*)&gcs[db + 2];
            float4 g45 = *(const float4*)&gcs[db + 4];
            float4 g67 = *(const float4*)&gcs[db + 6];
            float gx[8] = { g01.x, g01.z, g23.x, g23.z, g45.x, g45.z, g67.x, g67.z };
            float gy[8] = { g01.y, g01.w, g23.y, g23.w, g45.y, g45.w, g67.y, g67.w };
            #pragma unroll
            for (int u = 0; u < 8; ++u) {
                int off = (u == 0) ? 0 : (u + 1);
                float v = dxr[r][base - off];
                ar += v * gx[u]; ai += v * gy[u];
            }
            base -= 9; db += 8;
        }
        {
            float2 g = gcs[128];
            float v = dxr[r][base];
            ar += v * g.x; ai += v * g.y;
        }
        bool odd = (n & 1);
        float wr = odd ? -ar : ar, wi = odd ? ai : -ai;
        float2 cw = cs64[(n * sloc) & 63];               // w~ = w * conj(W)
        trti[r][s * 64 + n] = make_float2(wr * cw.x + wi * cw.y, wi * cw.x - wr * cw.y);
    }
    __syncthreads();

    // ---- P78: fused DFT64-band-select + IDFT32, pair-split over u (16 iters + shfl) ----
    {
        int slot = tid >> 1, h = tid & 1;
        int r = slot >> 8, t = slot & 255;
        int s = t >> 5, q = t & 31;
        const float2* wt = &trti[r][s * 64];
        float Wr = 0.f, Wi = 0.f, Ur = 0.f, Ui = 0.f;
        int ub = 16 * h;
        #pragma unroll 4
        for (int u = ub; u < ub + 16; ++u) {
            float2 a = wt[2 * u + 1];
            float w = ct[(2 * q - 2 * u - 1) & 63];
            Wr += a.x; Wi += a.y;
            Ur += a.x * w; Ui += a.y * w;
        }
        Wr += __shfl_xor(Wr, 1, 64); Wi += __shfl_xor(Wi, 1, 64);
        Ur += __shfl_xor(Ur, 1, 64); Ui += __shfl_xor(Ui, 1, 64);
        if (h == 0) {
            float2 e = wt[2 * q];
            float sgn = (q & 1) ? -S2048 : S2048;        // (-1)^q / sqrt2048
            float yr = sgn * (32.f * e.x + Wr - Ui);
            float yi = sgn * (32.f * e.y + Wi + Ur);
            ushort2 hv; hv.x = bf16_rne(yr); hv.y = bf16_rne(yi);
            *(ushort2*)&y5b[(size_t)(b0 + r) * 512 + (s * 32 + q) * 2] = hv;
        }
    }
}

extern "C" void kernel_launch(void* const* d_in, const int* in_sizes, int n_in,
                              void* d_out, int out_size, void* d_ws, size_t ws_size,
                              hipStream_t stream) {
    const float* x    = (const float*)d_in[0];
    const float* Wenc = (const float*)d_in[1];
    const float* benc = (const float*)d_in[2];
    const float* Wdec = (const float*)d_in[3];
    const float* bdec = (const float*)d_in[4];
    const float* rrc  = (const float*)d_in[5];
    const float* awgn = (const float*)d_in[6];
    const int* sloc   = (const int*)d_in[7];
    float* out = (float*)d_out;

    char* wsb = (char*)d_ws;
    ushort* w1t  = (ushort*)wsb;                     wsb += (size_t)512 * 3072 * 2;
    ushort* w2t  = (ushort*)wsb;                     wsb += (size_t)3072 * 512 * 2;
    ushort* y5b  = (ushort*)wsb;                     wsb += (size_t)1024 * 512 * 2;
    float*  papr = (float*)wsb;                      wsb += 1024 * 4;
    float*  zbuf = (float*)wsb;                      // partial: 8 x 1024x512 f32 (16.8 MB)
                                                     // fallback: 1024x512 f32 (2.1 MB)
    size_t head = (size_t)((char*)zbuf - (char*)d_ws);
    int partial = (ws_size >= head + (size_t)8 * 1024 * 512 * 4) ? 1 : 0;

    float* out_papr = out + (size_t)1024 * 3072;
    float* out_loss = out_papr + 1024;

    pack_k<<<partial ? 768 : 2816, 256, 0, stream>>>(Wenc, Wdec, benc, w1t, w2t, zbuf);
    gemm1_k<<<dim3(4, 16, 8), 256, 0, stream>>>(x, w1t, zbuf, 1024, 512, 3072, partial);
    mega_k<<<512, 1024, 0, stream>>>(zbuf, benc, rrc, awgn, sloc, y5b, papr, out_papr,
                                     partial ? 8 : 0);
    gemm2_k<<<dim3(48, 16, 1), 256, 0, stream>>>(y5b, w2t, bdec, papr, out, out_loss, 1024, 3072, 512);
}

// Round 8
// 148.124 us; speedup vs baseline: 1.0386x; 1.0386x over previous
//
#include <hip/hip_runtime.h>
#include <hip/hip_bf16.h>
#include <math.h>

#define L1_     5248
#define LENRRC_ 129
#define TSTART_ 65
#define NWIN_   5120
#define SWZ(m) ((m) + ((m) >> 3))     // stride-8 reads -> stride-9 -> conflict-free

typedef __attribute__((ext_vector_type(8))) short s16x8;   // 8 bf16 lanes (4 VGPRs)
typedef __attribute__((ext_vector_type(4))) float f32x4;   // MFMA accumulator

__device__ inline ushort bf16_rne(float x) {
    unsigned xb = __float_as_uint(x);
    return (ushort)((xb + 0x7fffu + ((xb >> 16) & 1u)) >> 16);
}

__device__ inline float wave_sum(float v) {
    #pragma unroll
    for (int m = 32; m > 0; m >>= 1) v += __shfl_xor(v, m, 64);
    return v;
}
__device__ inline float wave_max(float v) {
    #pragma unroll
    for (int m = 32; m > 0; m >>= 1) v = fmaxf(v, __shfl_xor(v, m, 64));
    return v;
}

// direct global->LDS 16B staging (dest = wave-uniform base + lane*16)
__device__ inline void gl_lds16(const void* g, void* l) {
    __builtin_amdgcn_global_load_lds(
        (const __attribute__((address_space(1))) unsigned int*)g,
        (__attribute__((address_space(3))) unsigned int*)l, 16, 0, 0);
}

// ---------- pack: W1^T bf16 | W2^T bf16 | (fallback: z=bias) ----------
__global__ __launch_bounds__(256) void pack_k(const float* __restrict__ W1,
        const float* __restrict__ W2, const float* __restrict__ benc,
        ushort* __restrict__ w1t, ushort* __restrict__ w2t, float* __restrict__ z)
{
    __shared__ ushort tile[64][70];
    const int blk = blockIdx.x, tid = threadIdx.x;
    if (blk < 768) {                                   // transpose W1 / W2 into bf16
        const float* W; ushort* T; int K, N, n0, k0;
        if (blk < 384) {
            int idx = blk;                             // grid (8,48)
            W = W1; T = w1t; K = 3072; N = 512;
            n0 = (idx & 7) * 64; k0 = (idx >> 3) * 64;
        } else {
            int idx = blk - 384;                       // grid (48,8)
            W = W2; T = w2t; K = 512; N = 3072;
            n0 = (idx % 48) * 64; k0 = (idx / 48) * 64;
        }
        const int cr = tid >> 4, cc = (tid & 15) * 4;
        #pragma unroll
        for (int i = 0; i < 4; ++i) {
            int kk = i * 16 + cr;
            float4 v = *(const float4*)&W[(size_t)(k0 + kk) * N + n0 + cc];
            tile[kk][cc]     = bf16_rne(v.x);
            tile[kk][cc + 1] = bf16_rne(v.y);
            tile[kk][cc + 2] = bf16_rne(v.z);
            tile[kk][cc + 3] = bf16_rne(v.w);
        }
        __syncthreads();
        #pragma unroll
        for (int i = 0; i < 4; ++i) {
            int nn = i * 16 + cr;
            ushort4 h;
            h.x = tile[cc][nn]; h.y = tile[cc + 1][nn];
            h.z = tile[cc + 2][nn]; h.w = tile[cc + 3][nn];
            *(ushort4*)&T[(size_t)(n0 + nn) * K + k0 + cc] = h;
        }
    } else {                                           // fallback only: init z with bias
        int i = (blk - 768) * 256 + tid;               // 524288 total
        z[i] = benc[i & 511];
    }
}

// ---------- gemm1: A from f32 x (cvt in-flight), B gl_lds, SK=4 partial panels ----------
__global__ __launch_bounds__(256) void gemm1_k(const float* __restrict__ Ax,
        const ushort* __restrict__ Bb, float* __restrict__ C, int M, int N, int K,
        int partial)
{
    __shared__ __attribute__((aligned(16))) ushort Asl[64 * 64];    // 8 KB, linear
    __shared__ __attribute__((aligned(16))) ushort Bsl[128 * 64];   // 16 KB, linear
    const int tid = threadIdx.x;
    const int lane = tid & 63, wave = tid >> 6;
    const int wm = (wave >> 1) * 32, wn = (wave & 1) * 64;
    const int m0 = blockIdx.y * 64, n0 = blockIdx.x * 128;
    const int kch = K / 4, kbeg = blockIdx.z * kch, kend = kbeg + kch;
    const int fm = lane & 15, q = lane >> 4;
    f32x4 acc[2][4] = {};

    // per-lane staging coords: chunk c -> (row, kb) with kb inverse-swizzled,
    // so linear LDS dest holds the XOR-swizzled layout (rule 21: both-sides)
    int arow[2], akb[2], brow[4], bkb[4];
    #pragma unroll
    for (int j = 0; j < 2; ++j) {
        int c = ((wave * 2 + j) << 6) + lane;
        arow[j] = c >> 3; akb[j] = (c & 7) ^ (arow[j] & 7);
    }
    #pragma unroll
    for (int j = 0; j < 4; ++j) {
        int c = ((wave * 4 + j) << 6) + lane;
        brow[j] = c >> 3; bkb[j] = (c & 7) ^ (brow[j] & 7);
    }

    for (int kt = kbeg; kt < kend; kt += 64) {
        #pragma unroll
        for (int j = 0; j < 4; ++j)                    // B 128x64: DMA first (overlaps A cvt)
            gl_lds16(&Bb[(size_t)(n0 + brow[j]) * K + kt + bkb[j] * 8],
                     &Bsl[(wave * 4 + j) << 9]);
        #pragma unroll
        for (int j = 0; j < 2; ++j) {                  // A 64x64: f32 load -> bf16 -> ds_write
            int c = ((wave * 2 + j) << 6) + lane;
            const float* src = &Ax[(size_t)(m0 + arow[j]) * K + kt + akb[j] * 8];
            float4 v0 = *(const float4*)src;
            float4 v1 = *(const float4*)(src + 4);
            s16x8 hv;
            hv[0] = (short)bf16_rne(v0.x); hv[1] = (short)bf16_rne(v0.y);
            hv[2] = (short)bf16_rne(v0.z); hv[3] = (short)bf16_rne(v0.w);
            hv[4] = (short)bf16_rne(v1.x); hv[5] = (short)bf16_rne(v1.y);
            hv[6] = (short)bf16_rne(v1.z); hv[7] = (short)bf16_rne(v1.w);
            *(s16x8*)&Asl[c * 8] = hv;
        }
        __syncthreads();                               // vmcnt+lgkm drain inserted here
        #pragma unroll
        for (int ks = 0; ks < 2; ++ks) {
            s16x8 a[2], b[4];
            #pragma unroll
            for (int mf = 0; mf < 2; ++mf) {
                int r = wm + mf * 16 + fm;
                a[mf] = *(const s16x8*)&Asl[(r << 6) + ((((ks << 2) + q) ^ (r & 7)) << 3)];
            }
            #pragma unroll
            for (int nf = 0; nf < 4; ++nf) {
                int r = wn + nf * 16 + fm;
                b[nf] = *(const s16x8*)&Bsl[(r << 6) + ((((ks << 2) + q) ^ (r & 7)) << 3)];
            }
            #pragma unroll
            for (int mf = 0; mf < 2; ++mf)
                #pragma unroll
                for (int nf = 0; nf < 4; ++nf)
                    acc[mf][nf] = __builtin_amdgcn_mfma_f32_16x16x32_bf16(a[mf], b[nf], acc[mf][nf], 0, 0, 0);
        }
        __syncthreads();
    }

    if (partial) {                                     // deterministic per-split panel
        float* Cs = C + (size_t)blockIdx.z * ((size_t)M * N);
        #pragma unroll
        for (int mf = 0; mf < 2; ++mf)
            #pragma unroll
            for (int nf = 0; nf < 4; ++nf)
                #pragma unroll
                for (int r = 0; r < 4; ++r) {
                    int m = m0 + wm + mf * 16 + q * 4 + r;
                    int n = n0 + wn + nf * 16 + fm;
                    Cs[(size_t)m * N + n] = acc[mf][nf][r];
                }
    } else {                                           // fallback: atomic accumulate
        #pragma unroll
        for (int mf = 0; mf < 2; ++mf)
            #pragma unroll
            for (int nf = 0; nf < 4; ++nf)
                #pragma unroll
                for (int r = 0; r < 4; ++r) {
                    int m = m0 + wm + mf * 16 + q * 4 + r;
                    int n = n0 + wn + nf * 16 + fm;
                    atomicAdd(&C[(size_t)m * N + n], acc[mf][nf][r]);
                }
    }
}

// ---------- gemm2: 64x64xBK64, global_load_lds + XOR-swizzle, + bias, fused PAPR loss ----------
__global__ __launch_bounds__(256) void gemm2_k(const ushort* __restrict__ Ab,
        const ushort* __restrict__ Bb, const float* __restrict__ bias,
        const float* __restrict__ papr, float* __restrict__ C,
        float* __restrict__ out_loss, int M, int N, int K)
{
    __shared__ __attribute__((aligned(16))) ushort Asl[64 * 64];
    __shared__ __attribute__((aligned(16))) ushort Bsl[64 * 64];
    __shared__ float red[4];
    const int tid = threadIdx.x;
    const int lane = tid & 63, wave = tid >> 6;
    const int wm = (wave >> 1) * 32, wn = (wave & 1) * 32;
    const int m0 = blockIdx.y * 64, n0 = blockIdx.x * 64;
    const int fm = lane & 15, q = lane >> 4;
    f32x4 acc[2][2] = {};

    int srow[2], skb[2];
    #pragma unroll
    for (int j = 0; j < 2; ++j) {
        int c = ((wave * 2 + j) << 6) + lane;
        srow[j] = c >> 3; skb[j] = (c & 7) ^ (srow[j] & 7);
    }

    for (int kt = 0; kt < K; kt += 64) {
        #pragma unroll
        for (int j = 0; j < 2; ++j) {
            gl_lds16(&Ab[(size_t)(m0 + srow[j]) * K + kt + skb[j] * 8],
                     &Asl[(wave * 2 + j) << 9]);
            gl_lds16(&Bb[(size_t)(n0 + srow[j]) * K + kt + skb[j] * 8],
                     &Bsl[(wave * 2 + j) << 9]);
        }
        __syncthreads();
        #pragma unroll
        for (int ks = 0; ks < 2; ++ks) {
            s16x8 a[2], b[2];
            #pragma unroll
            for (int mf = 0; mf < 2; ++mf) {
                int r = wm + mf * 16 + fm;
                a[mf] = *(const s16x8*)&Asl[(r << 6) + ((((ks << 2) + q) ^ (r & 7)) << 3)];
            }
            #pragma unroll
            for (int nf = 0; nf < 2; ++nf) {
                int r = wn + nf * 16 + fm;
                b[nf] = *(const s16x8*)&Bsl[(r << 6) + ((((ks << 2) + q) ^ (r & 7)) << 3)];
            }
            #pragma unroll
            for (int mf = 0; mf < 2; ++mf)
                #pragma unroll
                for (int nf = 0; nf < 2; ++nf)
                    acc[mf][nf] = __builtin_amdgcn_mfma_f32_16x16x32_bf16(a[mf], b[nf], acc[mf][nf], 0, 0, 0);
        }
        __syncthreads();
    }

    #pragma unroll
    for (int mf = 0; mf < 2; ++mf)
        #pragma unroll
        for (int nf = 0; nf < 2; ++nf)
            #pragma unroll
            for (int r = 0; r < 4; ++r) {
                int m = m0 + wm + mf * 16 + q * 4 + r;
                int n = n0 + wn + nf * 16 + fm;
                C[(size_t)m * N + n] = acc[mf][nf][r] + bias[n];
            }

    if (blockIdx.x == 0 && blockIdx.y == 0) {          // fused PAPR loss
        float s = 0.f;
        for (int i = tid; i < 1024; i += 256) { float v = papr[i] - 8.f; s += v > 0.f ? v : 0.f; }
        s = wave_sum(s);
        if (lane == 0) red[wave] = s;
        __syncthreads();
        if (tid == 0) *out_loss = (red[0] + red[1] + red[2] + red[3]) * (1.f / 1024.f);
    }
}

// ---------- megakernel: 2 rows/block, collapsed DFTs (P12/P78 via cot identity) ----------
// P1+P2 == IDFT64(fftshift(DFT32(z))): with z~[q]=(-1)^q z[q],
//   d[2m]  = (1/sqrt2) * e^{2pi i 2m sloc/64} * z~[m]                   (interpolation identity)
//   d[odd n] = (1/sqrt2048) * e^{2pi i n sloc/64} * ( Sum z~ + i * Sum z~[q] cot(pi(n-2q)/64) )
// P7+P8 is the adjoint with identical structure on w~[n] = w[n] e^{-2pi i n sloc/64}.
__global__ __launch_bounds__(512, 4) void mega_k(const float* __restrict__ z,
        const float* __restrict__ benc,
        const float* __restrict__ rrc, const float* __restrict__ awgn,
        const int* __restrict__ slocp, ushort* __restrict__ y5b,
        float* __restrict__ papr, float* __restrict__ out_papr, int nsp)
{
    __shared__ float  zl[2][512];
    __shared__ float2 trti[2][672];    // P12 out (CP layout) / reused as w~[s*64+n] after P6
    __shared__ float  hl[132];
    __shared__ float  csl[16], ssl[16];
    __shared__ float2 cs64[64];
    __shared__ float  ct[64];          // cot(pi*j/64), odd j only
    __shared__ __attribute__((aligned(16))) float2 gcs[130];
    __shared__ float  dxr[2][SWZ(L1_ - 1) + 1];
    __shared__ float  red[2][8], red2[2][8];

    const int b0 = blockIdx.x * 2, b1 = b0 + 1;
    const int tid = threadIdx.x;
    const int lane = tid & 63, wv = tid >> 6;
    const int sloc = *slocp;
    const float S2048 = 0.02209708691207961f;            // 1/sqrt(2048)

    // ---- tables ----
    if (tid < 64) {
        float ang = 0.09817477042468103f * (float)tid;   // 2pi/64
        float s, c; sincosf(ang, &s, &c);
        cs64[tid] = make_float2(c, s);
    }
    if (tid >= 64 && tid < 80) {
        int t = tid - 64;
        float ang = 1.9634954084936207f * (float)t;      // 2pi*5/16
        float s, c; sincosf(ang, &s, &c);
        csl[t] = 1.4142135623730951f * c; ssl[t] = 1.4142135623730951f * s;
    }
    if (tid >= 96 && tid < 160) {                        // trti zero pads, both rows
        int t = (tid - 96) & 31, row = (tid - 96) >> 5;
        int idx = (t < 16) ? t : (640 + t);              // [0..15] and [656..671]
        trti[row][idx] = make_float2(0.f, 0.f);
    }
    if (tid >= 160 && tid < 224) {                       // cot table (odd entries)
        int j = tid - 160;
        float v = 0.f;
        if (j & 1) { float s, c; sincosf(0.04908738521234052f * (float)j, &s, &c); v = c / s; }
        ct[j] = v;
    }
    if (tid >= 256 && tid < 256 + LENRRC_) hl[tid - 256] = rrc[tid - 256];

    // ---- z rows: bias + sum of split-K partial panels (or prereduced fallback) ----
    float va, vb;
    if (nsp) {
        va = benc[tid]; vb = va;
        const float* zp0 = z + (size_t)b0 * 512;
        const float* zp1 = z + (size_t)b1 * 512;
        for (int s = 0; s < nsp; ++s) {
            va += zp0[(size_t)s * 524288 + tid];
            vb += zp1[(size_t)s * 524288 + tid];
        }
    } else {
        va = z[(size_t)b0 * 512 + tid];
        vb = z[(size_t)b1 * 512 + tid];
    }
    __syncthreads();

    // ---- gcs: carrier folded into RRC taps ----
    if (tid < LENRRC_) {
        int neg = (16 - (tid & 15)) & 15;                // (-d) & 15
        gcs[tid] = make_float2(hl[tid] * csl[neg], hl[tid] * ssl[neg]);
    }

    // ---- power norm (single pass: S, Q; ddof=1), both rows; fold (-1)^q into zl ----
    {
        float S0 = wave_sum(va), Q0 = wave_sum(va * va);
        float S1 = wave_sum(vb), Q1 = wave_sum(vb * vb);
        if (lane == 0) { red[0][wv] = S0; red2[0][wv] = Q0; red[1][wv] = S1; red2[1][wv] = Q1; }
    }
    __syncthreads();
    {
        float S0 = 0.f, Q0 = 0.f, S1 = 0.f, Q1 = 0.f;
        #pragma unroll
        for (int w = 0; w < 8; ++w) {
            S0 += red[0][w]; Q0 += red2[0][w];
            S1 += red[1][w]; Q1 += red2[1][w];
        }
        float m0 = S0 * (1.f / 512.f), m1 = S1 * (1.f / 512.f);
        float i0 = 1.f / (sqrtf((Q0 - S0 * m0) * (1.f / 511.f)) + 1e-8f);
        float i1 = 1.f / (sqrtf((Q1 - S1 * m1) * (1.f / 511.f)) + 1e-8f);
        float sg = ((tid >> 1) & 1) ? -1.f : 1.f;        // (-1)^q, q = tid>>1
        zl[0][tid] = (va - m0) * i0 * sg;
        zl[1][tid] = (vb - m1) * i1 * sg;
    }
    __syncthreads();

    // ---- P12: fused DFT32+IDFT64+CP. Each thread: 1 odd + 1 even output of its row ----
    {
        int r = tid >> 8, t = tid & 255;
        int s = t >> 5, j = t & 31;
        int base = s * 80;                               // data at [base+32 .. base+95]
        const float2* zs = (const float2*)&zl[r][s * 64];
        // odd n = 2j+1: dense cot sum
        int n = 2 * j + 1;
        float Zr = 0.f, Zi = 0.f, Tr = 0.f, Ti = 0.f;
        #pragma unroll 4
        for (int q = 0; q < 32; ++q) {
            float2 a = zs[q];
            float w = ct[(n - 2 * q) & 63];
            Zr += a.x; Zi += a.y;
            Tr += a.x * w; Ti += a.y * w;
        }
        {
            float2 cw = cs64[(n * sloc) & 63];
            float Ar = Zr - Ti, Ai = Zi + Tr;            // Z + i*T
            float dr = S2048 * (Ar * cw.x - Ai * cw.y);
            float di = S2048 * (Ai * cw.x + Ar * cw.y);
            trti[r][base + 32 + n] = make_float2(dr, di);
            if (n >= 48) trti[r][base + n - 32] = make_float2(dr, di);   // CP
        }
        // even n = 2j: trivial (interpolation identity)
        {
            int n2 = 2 * j;
            float2 a = zs[j];
            float2 cw = cs64[(n2 * sloc) & 63];
            const float RS2 = 0.7071067811865476f;       // 1/sqrt2
            float dr = RS2 * (a.x * cw.x - a.y * cw.y);
            float di = RS2 * (a.y * cw.x + a.x * cw.y);
            trti[r][base + 32 + n2] = make_float2(dr, di);
            if (n2 >= 48) trti[r][base + n2 - 32] = make_float2(dr, di); // CP
        }
    }
    __syncthreads();

    // ---- P3: upsample x8 + RRC polyphase + carrier, task=(a,g), both rows share hl ----
    float ss0 = 0.f, ss1 = 0.f;
    for (int tsk = tid; tsk < 1312; tsk += 512) {
        int a = tsk >> 1, g = tsk & 1;
        float ar0[4] = {}, ai0[4] = {}, ar1[4] = {}, ai1[4] = {};
        #pragma unroll 4
        for (int d = 0; d < 16; ++d) {
            float2 t0 = trti[0][16 + a - d];             // zero-padded: no bounds check
            float2 t1 = trti[1][16 + a - d];
            #pragma unroll
            for (int r = 0; r < 4; ++r) {
                float h = hl[g * 4 + r + 8 * d];
                ar0[r] += t0.x * h; ai0[r] += t0.y * h;
                ar1[r] += t1.x * h; ai1[r] += t1.y * h;
            }
        }
        if (g == 0) {                                    // d=16, tap 128, r=0 only
            float2 t0 = trti[0][a], t1 = trti[1][a];
            float h = hl[128];
            ar0[0] += t0.x * h; ai0[0] += t0.y * h;
            ar1[0] += t1.x * h; ai1[0] += t1.y * h;
        }
        int cb = (a & 1) * 8;
        #pragma unroll
        for (int r = 0; r < 4; ++r) {
            int rr = g * 4 + r;
            float cv = csl[cb + rr], sv = ssl[cb + rr];
            float v0 = ar0[r] * cv - ai0[r] * sv;
            float v1 = ar1[r] * cv - ai1[r] * sv;
            dxr[0][SWZ(a * 8 + rr)] = v0;
            dxr[1][SWZ(a * 8 + rr)] = v1;
            ss0 += v0 * v0; ss1 += v1 * v1;
        }
    }
    ss0 = wave_sum(ss0); ss1 = wave_sum(ss1);
    if (lane == 0) { red[0][wv] = ss0; red[1][wv] = ss1; }
    __syncthreads();
    float thr0, thr1;
    {
        float S0 = 0.f, S1 = 0.f;
        #pragma unroll
        for (int w = 0; w < 8; ++w) { S0 += red[0][w]; S1 += red[1][w]; }
        thr0 = 1.2f * sqrtf(S0 / (float)L1_);
        thr1 = 1.2f * sqrtf(S1 / (float)L1_);
    }
    __syncthreads();

    // ---- P5: clip + PAPR window stats + AWGN (in place), both rows ----
    float pm0 = 0.f, ps0 = 0.f, pm1 = 0.f, ps1 = 0.f;
    {
        const float4* ag0 = (const float4*)&awgn[(size_t)b0 * L1_];
        const float4* ag1 = (const float4*)&awgn[(size_t)b1 * L1_];
        for (int ii = tid; ii < 1312; ii += 512) {       // 1312*4 = 5248
            float4 a0 = ag0[ii], a1 = ag1[ii];
            int i = ii * 4;
            #pragma unroll
            for (int e = 0; e < 4; ++e) {
                int idx = i + e;
                bool win = (idx >= TSTART_ && idx < TSTART_ + NWIN_);
                float aw0 = (e == 0) ? a0.x : (e == 1) ? a0.y : (e == 2) ? a0.z : a0.w;
                float aw1 = (e == 0) ? a1.x : (e == 1) ? a1.y : (e == 2) ? a1.z : a1.w;
                {
                    float x = dxr[0][SWZ(idx)];
                    float ax = fabsf(x);
                    float over = fmaxf(ax - thr0, 0.f);
                    float y = (1.f - over / (ax + 1e-8f)) * x;
                    if (win) { float p = y * y; ps0 += p; pm0 = fmaxf(pm0, p); }
                    dxr[0][SWZ(idx)] = y + aw0;
                }
                {
                    float x = dxr[1][SWZ(idx)];
                    float ax = fabsf(x);
                    float over = fmaxf(ax - thr1, 0.f);
                    float y = (1.f - over / (ax + 1e-8f)) * x;
                    if (win) { float p = y * y; ps1 += p; pm1 = fmaxf(pm1, p); }
                    dxr[1][SWZ(idx)] = y + aw1;
                }
            }
        }
    }
    ps0 = wave_sum(ps0); pm0 = wave_max(pm0);
    ps1 = wave_sum(ps1); pm1 = wave_max(pm1);
    if (lane == 0) { red[0][wv] = ps0; red2[0][wv] = pm0; red[1][wv] = ps1; red2[1][wv] = pm1; }
    __syncthreads();
    if (tid == 0) {
        float s0 = 0.f, m0 = 0.f, s1 = 0.f, m1 = 0.f;
        #pragma unroll
        for (int w = 0; w < 8; ++w) {
            s0 += red[0][w]; m0 = fmaxf(m0, red2[0][w]);
            s1 += red[1][w]; m1 = fmaxf(m1, red2[1][w]);
        }
        float p0 = 10.f * log10f(m0 / (s0 / (float)NWIN_));
        float p1 = 10.f * log10f(m1 / (s1 / (float)NWIN_));
        papr[b0] = p0; out_papr[b0] = p0;
        papr[b1] = p1; out_papr[b1] = p1;
    }
    __syncthreads();     // all P5 dxr writes visible before P6

    // ---- P6: matched RRC filter -> w~[n] = w[n]*conj(W[n*sloc]) into trti[s*64+n] ----
    {
        int s = wv, n = lane;                            // 8 waves x 64 outputs, both rows
        int T0 = s * 80 + n + 32;                        // Nf/8
        int base = 9 * T0;                               // SWZ(Nf)
        float ar0 = 0.f, ai0 = 0.f, ar1 = 0.f, ai1 = 0.f;
        int db = 0;
        #pragma unroll 4
        for (int e = 0; e < 16; ++e) {
            float4 g01 = *(const float4*)&gcs[db];       // gcs[db], gcs[db+1]
            float4 g23 = *(const float4*)&gcs[db + 2];
            float4 g45 = *(const float4*)&gcs[db + 4];
            float4 g67 = *(const float4*)&gcs[db + 6];
            float gx[8] = { g01.x, g01.z, g23.x, g23.z, g45.x, g45.z, g67.x, g67.z };
            float gy[8] = { g01.y, g01.w, g23.y, g23.w, g45.y, g45.w, g67.y, g67.w };
            #pragma unroll
            for (int u = 0; u < 8; ++u) {
                int off = (u == 0) ? 0 : (u + 1);
                float v0 = dxr[0][base - off];
                float v1 = dxr[1][base - off];
                ar0 += v0 * gx[u]; ai0 += v0 * gy[u];
                ar1 += v1 * gx[u]; ai1 += v1 * gy[u];
            }
            base -= 9; db += 8;
        }
        {
            float2 g = gcs[128];
            float v0 = dxr[0][base], v1 = dxr[1][base];
            ar0 += v0 * g.x; ai0 += v0 * g.y;
            ar1 += v1 * g.x; ai1 += v1 * g.y;
        }
        bool odd = (n & 1);
        float wr0 = odd ? -ar0 : ar0, wi0 = odd ? ai0 : -ai0;
        float wr1 = odd ? -ar1 : ar1, wi1 = odd ? ai1 : -ai1;
        float2 cw = cs64[(n * sloc) & 63];               // w~ = w * conj(W)
        trti[0][s * 64 + n] = make_float2(wr0 * cw.x + wi0 * cw.y, wi0 * cw.x - wr0 * cw.y);
        trti[1][s * 64 + n] = make_float2(wr1 * cw.x + wi1 * cw.y, wi1 * cw.x - wr1 * cw.y);
    }
    __syncthreads();

    // ---- P78: fused DFT64-band-select + IDFT32 via cot identity -> y5b bf16 ----
    {
        int r = tid >> 8, t = tid & 255;
        int s = t >> 5, q = t & 31;
        const float2* wt = &trti[r][s * 64];
        float Wr = 0.f, Wi = 0.f, Ur = 0.f, Ui = 0.f;
        #pragma unroll 4
        for (int u = 0; u < 32; ++u) {
            float2 a = wt[2 * u + 1];
            float w = ct[(2 * q - 2 * u - 1) & 63];
            Wr += a.x; Wi += a.y;
            Ur += a.x * w; Ui += a.y * w;
        }
        float2 e = wt[2 * q];
        float sgn = (q & 1) ? -S2048 : S2048;            // (-1)^q / sqrt2048
        float yr = sgn * (32.f * e.x + Wr - Ui);
        float yi = sgn * (32.f * e.y + Wi + Ur);
        ushort2 h; h.x = bf16_rne(yr); h.y = bf16_rne(yi);
        *(ushort2*)&y5b[(size_t)(b0 + r) * 512 + (s * 32 + q) * 2] = h;
    }
}

extern "C" void kernel_launch(void* const* d_in, const int* in_sizes, int n_in,
                              void* d_out, int out_size, void* d_ws, size_t ws_size,
                              hipStream_t stream) {
    const float* x    = (const float*)d_in[0];
    const float* Wenc = (const float*)d_in[1];
    const float* benc = (const float*)d_in[2];
    const float* Wdec = (const float*)d_in[3];
    const float* bdec = (const float*)d_in[4];
    const float* rrc  = (const float*)d_in[5];
    const float* awgn = (const float*)d_in[6];
    const int* sloc   = (const int*)d_in[7];
    float* out = (float*)d_out;

    char* wsb = (char*)d_ws;
    ushort* w1t  = (ushort*)wsb;                     wsb += (size_t)512 * 3072 * 2;
    ushort* w2t  = (ushort*)wsb;                     wsb += (size_t)3072 * 512 * 2;
    ushort* y5b  = (ushort*)wsb;                     wsb += (size_t)1024 * 512 * 2;
    float*  papr = (float*)wsb;                      wsb += 1024 * 4;
    float*  zbuf = (float*)wsb;                      // partial: 4 x 1024x512 f32 (8.4 MB)
                                                     // fallback: 1024x512 f32 (2.1 MB)
    size_t head = (size_t)((char*)zbuf - (char*)d_ws);
    const int SK = 4;
    int partial = (ws_size >= head + (size_t)SK * 1024 * 512 * 4) ? 1 : 0;

    float* out_papr = out + (size_t)1024 * 3072;
    float* out_loss = out_papr + 1024;

    pack_k<<<partial ? 768 : 2816, 256, 0, stream>>>(Wenc, Wdec, benc, w1t, w2t, zbuf);
    gemm1_k<<<dim3(4, 16, SK), 256, 0, stream>>>(x, w1t, zbuf, 1024, 512, 3072, partial);
    mega_k<<<512, 512, 0, stream>>>(zbuf, benc, rrc, awgn, sloc, y5b, papr, out_papr,
                                    partial ? SK : 0);
    gemm2_k<<<dim3(48, 16, 1), 256, 0, stream>>>(y5b, w2t, bdec, papr, out, out_loss, 1024, 3072, 512);
}

// Round 9
// 144.859 us; speedup vs baseline: 1.0620x; 1.0225x over previous
//
#include <hip/hip_runtime.h>
#include <hip/hip_bf16.h>
#include <math.h>

#define L1_     5248
#define LENRRC_ 129
#define TSTART_ 65
#define NWIN_   5120
#define SWZ(m) ((m) + ((m) >> 3))     // stride-8 reads -> stride-9 -> conflict-free

typedef __attribute__((ext_vector_type(8))) short s16x8;   // 8 bf16 lanes (4 VGPRs)
typedef __attribute__((ext_vector_type(4))) float f32x4;   // MFMA accumulator

__device__ inline ushort bf16_rne(float x) {
    unsigned xb = __float_as_uint(x);
    return (ushort)((xb + 0x7fffu + ((xb >> 16) & 1u)) >> 16);
}

__device__ inline float wave_sum(float v) {
    #pragma unroll
    for (int m = 32; m > 0; m >>= 1) v += __shfl_xor(v, m, 64);
    return v;
}
__device__ inline float wave_max(float v) {
    #pragma unroll
    for (int m = 32; m > 0; m >>= 1) v = fmaxf(v, __shfl_xor(v, m, 64));
    return v;
}

// direct global->LDS 16B staging (dest = wave-uniform base + lane*16)
__device__ inline void gl_lds16(const void* g, void* l) {
    __builtin_amdgcn_global_load_lds(
        (const __attribute__((address_space(1))) unsigned int*)g,
        (__attribute__((address_space(3))) unsigned int*)l, 16, 0, 0);
}

// ---------- pack: W1^T bf16 | W2^T bf16 | (fallback: z=bias) ----------
__global__ __launch_bounds__(256) void pack_k(const float* __restrict__ W1,
        const float* __restrict__ W2, const float* __restrict__ benc,
        ushort* __restrict__ w1t, ushort* __restrict__ w2t, float* __restrict__ z)
{
    __shared__ ushort tile[64][70];
    const int blk = blockIdx.x, tid = threadIdx.x;
    if (blk < 768) {                                   // transpose W1 / W2 into bf16
        const float* W; ushort* T; int K, N, n0, k0;
        if (blk < 384) {
            int idx = blk;                             // grid (8,48)
            W = W1; T = w1t; K = 3072; N = 512;
            n0 = (idx & 7) * 64; k0 = (idx >> 3) * 64;
        } else {
            int idx = blk - 384;                       // grid (48,8)
            W = W2; T = w2t; K = 512; N = 3072;
            n0 = (idx % 48) * 64; k0 = (idx / 48) * 64;
        }
        const int cr = tid >> 4, cc = (tid & 15) * 4;
        #pragma unroll
        for (int i = 0; i < 4; ++i) {
            int kk = i * 16 + cr;
            float4 v = *(const float4*)&W[(size_t)(k0 + kk) * N + n0 + cc];
            tile[kk][cc]     = bf16_rne(v.x);
            tile[kk][cc + 1] = bf16_rne(v.y);
            tile[kk][cc + 2] = bf16_rne(v.z);
            tile[kk][cc + 3] = bf16_rne(v.w);
        }
        __syncthreads();
        #pragma unroll
        for (int i = 0; i < 4; ++i) {
            int nn = i * 16 + cr;
            ushort4 h;
            h.x = tile[cc][nn]; h.y = tile[cc + 1][nn];
            h.z = tile[cc + 2][nn]; h.w = tile[cc + 3][nn];
            *(ushort4*)&T[(size_t)(n0 + nn) * K + k0 + cc] = h;
        }
    } else {                                           // fallback only: init z with bias
        int i = (blk - 768) * 256 + tid;               // 524288 total
        z[i] = benc[i & 511];
    }
}

// ---------- gemm1: A from f32 x (cvt in-flight), B gl_lds, SK=8 partial panels ----------
__global__ __launch_bounds__(256) void gemm1_k(const float* __restrict__ Ax,
        const ushort* __restrict__ Bb, float* __restrict__ C, int M, int N, int K,
        int partial)
{
    __shared__ __attribute__((aligned(16))) ushort Asl[64 * 64];    // 8 KB, linear
    __shared__ __attribute__((aligned(16))) ushort Bsl[128 * 64];   // 16 KB, linear
    const int tid = threadIdx.x;
    const int lane = tid & 63, wave = tid >> 6;
    const int wm = (wave >> 1) * 32, wn = (wave & 1) * 64;
    const int m0 = blockIdx.y * 64, n0 = blockIdx.x * 128;
    const int kch = K / 8, kbeg = blockIdx.z * kch, kend = kbeg + kch;
    const int fm = lane & 15, q = lane >> 4;
    f32x4 acc[2][4] = {};

    // per-lane staging coords: chunk c -> (row, kb) with kb inverse-swizzled,
    // so linear LDS dest holds the XOR-swizzled layout (rule 21: both-sides)
    int arow[2], akb[2], brow[4], bkb[4];
    #pragma unroll
    for (int j = 0; j < 2; ++j) {
        int c = ((wave * 2 + j) << 6) + lane;
        arow[j] = c >> 3; akb[j] = (c & 7) ^ (arow[j] & 7);
    }
    #pragma unroll
    for (int j = 0; j < 4; ++j) {
        int c = ((wave * 4 + j) << 6) + lane;
        brow[j] = c >> 3; bkb[j] = (c & 7) ^ (brow[j] & 7);
    }

    for (int kt = kbeg; kt < kend; kt += 64) {
        #pragma unroll
        for (int j = 0; j < 4; ++j)                    // B 128x64: DMA first (overlaps A cvt)
            gl_lds16(&Bb[(size_t)(n0 + brow[j]) * K + kt + bkb[j] * 8],
                     &Bsl[(wave * 4 + j) << 9]);
        #pragma unroll
        for (int j = 0; j < 2; ++j) {                  // A 64x64: f32 load -> bf16 -> ds_write
            int c = ((wave * 2 + j) << 6) + lane;
            const float* src = &Ax[(size_t)(m0 + arow[j]) * K + kt + akb[j] * 8];
            float4 v0 = *(const float4*)src;
            float4 v1 = *(const float4*)(src + 4);
            s16x8 hv;
            hv[0] = (short)bf16_rne(v0.x); hv[1] = (short)bf16_rne(v0.y);
            hv[2] = (short)bf16_rne(v0.z); hv[3] = (short)bf16_rne(v0.w);
            hv[4] = (short)bf16_rne(v1.x); hv[5] = (short)bf16_rne(v1.y);
            hv[6] = (short)bf16_rne(v1.z); hv[7] = (short)bf16_rne(v1.w);
            *(s16x8*)&Asl[c * 8] = hv;
        }
        __syncthreads();                               // vmcnt+lgkm drain inserted here
        #pragma unroll
        for (int ks = 0; ks < 2; ++ks) {
            s16x8 a[2], b[4];
            #pragma unroll
            for (int mf = 0; mf < 2; ++mf) {
                int r = wm + mf * 16 + fm;
                a[mf] = *(const s16x8*)&Asl[(r << 6) + ((((ks << 2) + q) ^ (r & 7)) << 3)];
            }
            #pragma unroll
            for (int nf = 0; nf < 4; ++nf) {
                int r = wn + nf * 16 + fm;
                b[nf] = *(const s16x8*)&Bsl[(r << 6) + ((((ks << 2) + q) ^ (r & 7)) << 3)];
            }
            #pragma unroll
            for (int mf = 0; mf < 2; ++mf)
                #pragma unroll
                for (int nf = 0; nf < 4; ++nf)
                    acc[mf][nf] = __builtin_amdgcn_mfma_f32_16x16x32_bf16(a[mf], b[nf], acc[mf][nf], 0, 0, 0);
        }
        __syncthreads();
    }

    if (partial) {                                     // deterministic per-split panel
        float* Cs = C + (size_t)blockIdx.z * ((size_t)M * N);
        #pragma unroll
        for (int mf = 0; mf < 2; ++mf)
            #pragma unroll
            for (int nf = 0; nf < 4; ++nf)
                #pragma unroll
                for (int r = 0; r < 4; ++r) {
                    int m = m0 + wm + mf * 16 + q * 4 + r;
                    int n = n0 + wn + nf * 16 + fm;
                    Cs[(size_t)m * N + n] = acc[mf][nf][r];
                }
    } else {                                           // fallback: atomic accumulate
        #pragma unroll
        for (int mf = 0; mf < 2; ++mf)
            #pragma unroll
            for (int nf = 0; nf < 4; ++nf)
                #pragma unroll
                for (int r = 0; r < 4; ++r) {
                    int m = m0 + wm + mf * 16 + q * 4 + r;
                    int n = n0 + wn + nf * 16 + fm;
                    atomicAdd(&C[(size_t)m * N + n], acc[mf][nf][r]);
                }
    }
}

// ---------- gemm2: 64x64xBK64, global_load_lds + XOR-swizzle, + bias, fused PAPR loss ----------
__global__ __launch_bounds__(256) void gemm2_k(const ushort* __restrict__ Ab,
        const ushort* __restrict__ Bb, const float* __restrict__ bias,
        const float* __restrict__ papr, float* __restrict__ C,
        float* __restrict__ out_loss, int M, int N, int K)
{
    __shared__ __attribute__((aligned(16))) ushort Asl[64 * 64];
    __shared__ __attribute__((aligned(16))) ushort Bsl[64 * 64];
    __shared__ float red[4];
    const int tid = threadIdx.x;
    const int lane = tid & 63, wave = tid >> 6;
    const int wm = (wave >> 1) * 32, wn = (wave & 1) * 32;
    const int m0 = blockIdx.y * 64, n0 = blockIdx.x * 64;
    const int fm = lane & 15, q = lane >> 4;
    f32x4 acc[2][2] = {};

    int srow[2], skb[2];
    #pragma unroll
    for (int j = 0; j < 2; ++j) {
        int c = ((wave * 2 + j) << 6) + lane;
        srow[j] = c >> 3; skb[j] = (c & 7) ^ (srow[j] & 7);
    }

    for (int kt = 0; kt < K; kt += 64) {
        #pragma unroll
        for (int j = 0; j < 2; ++j) {
            gl_lds16(&Ab[(size_t)(m0 + srow[j]) * K + kt + skb[j] * 8],
                     &Asl[(wave * 2 + j) << 9]);
            gl_lds16(&Bb[(size_t)(n0 + srow[j]) * K + kt + skb[j] * 8],
                     &Bsl[(wave * 2 + j) << 9]);
        }
        __syncthreads();
        #pragma unroll
        for (int ks = 0; ks < 2; ++ks) {
            s16x8 a[2], b[2];
            #pragma unroll
            for (int mf = 0; mf < 2; ++mf) {
                int r = wm + mf * 16 + fm;
                a[mf] = *(const s16x8*)&Asl[(r << 6) + ((((ks << 2) + q) ^ (r & 7)) << 3)];
            }
            #pragma unroll
            for (int nf = 0; nf < 2; ++nf) {
                int r = wn + nf * 16 + fm;
                b[nf] = *(const s16x8*)&Bsl[(r << 6) + ((((ks << 2) + q) ^ (r & 7)) << 3)];
            }
            #pragma unroll
            for (int mf = 0; mf < 2; ++mf)
                #pragma unroll
                for (int nf = 0; nf < 2; ++nf)
                    acc[mf][nf] = __builtin_amdgcn_mfma_f32_16x16x32_bf16(a[mf], b[nf], acc[mf][nf], 0, 0, 0);
        }
        __syncthreads();
    }

    #pragma unroll
    for (int mf = 0; mf < 2; ++mf)
        #pragma unroll
        for (int nf = 0; nf < 2; ++nf)
            #pragma unroll
            for (int r = 0; r < 4; ++r) {
                int m = m0 + wm + mf * 16 + q * 4 + r;
                int n = n0 + wn + nf * 16 + fm;
                C[(size_t)m * N + n] = acc[mf][nf][r] + bias[n];
            }

    if (blockIdx.x == 0 && blockIdx.y == 0) {          // fused PAPR loss
        float s = 0.f;
        for (int i = tid; i < 1024; i += 256) { float v = papr[i] - 8.f; s += v > 0.f ? v : 0.f; }
        s = wave_sum(s);
        if (lane == 0) red[wave] = s;
        __syncthreads();
        if (tid == 0) *out_loss = (red[0] + red[1] + red[2] + red[3]) * (1.f / 1024.f);
    }
}

// ---------- megakernel: 2 rows/block, collapsed DFTs (P12/P78 via cot identity) ----------
// P1+P2 == IDFT64(fftshift(DFT32(z))): with z~[q]=(-1)^q z[q],
//   d[2m]  = (1/sqrt2) * e^{2pi i 2m sloc/64} * z~[m]                   (interpolation identity)
//   d[odd n] = (1/sqrt2048) * e^{2pi i n sloc/64} * ( Sum z~ + i * Sum z~[q] cot(pi(n-2q)/64) )
// P7+P8 is the adjoint with identical structure on w~[n] = w[n] e^{-2pi i n sloc/64}.
__global__ __launch_bounds__(512, 4) void mega_k(const float* __restrict__ z,
        const float* __restrict__ benc,
        const float* __restrict__ rrc, const float* __restrict__ awgn,
        const int* __restrict__ slocp, ushort* __restrict__ y5b,
        float* __restrict__ papr, float* __restrict__ out_papr, int nsp)
{
    __shared__ float  zl[2][512];
    __shared__ float2 trti[2][672];    // P12 out (CP layout) / reused as w~[s*64+n] after P6
    __shared__ float  hl[132];
    __shared__ float  csl[16], ssl[16];
    __shared__ float2 cs64[64];
    __shared__ float  ct[64];          // cot(pi*j/64), odd j only
    __shared__ __attribute__((aligned(16))) float2 gcs[130];
    __shared__ float  dxr[2][SWZ(L1_ - 1) + 1];
    __shared__ float  red[2][8], red2[2][8];

    const int b0 = blockIdx.x * 2, b1 = b0 + 1;
    const int tid = threadIdx.x;
    const int lane = tid & 63, wv = tid >> 6;
    const int sloc = *slocp;
    const float S2048 = 0.02209708691207961f;            // 1/sqrt(2048)

    // ---- tables ----
    if (tid < 64) {
        float ang = 0.09817477042468103f * (float)tid;   // 2pi/64
        float s, c; sincosf(ang, &s, &c);
        cs64[tid] = make_float2(c, s);
    }
    if (tid >= 64 && tid < 80) {
        int t = tid - 64;
        float ang = 1.9634954084936207f * (float)t;      // 2pi*5/16
        float s, c; sincosf(ang, &s, &c);
        csl[t] = 1.4142135623730951f * c; ssl[t] = 1.4142135623730951f * s;
    }
    if (tid >= 96 && tid < 160) {                        // trti zero pads, both rows
        int t = (tid - 96) & 31, row = (tid - 96) >> 5;
        int idx = (t < 16) ? t : (640 + t);              // [0..15] and [656..671]
        trti[row][idx] = make_float2(0.f, 0.f);
    }
    if (tid >= 160 && tid < 224) {                       // cot table (odd entries)
        int j = tid - 160;
        float v = 0.f;
        if (j & 1) { float s, c; sincosf(0.04908738521234052f * (float)j, &s, &c); v = c / s; }
        ct[j] = v;
    }
    if (tid >= 256 && tid < 256 + LENRRC_) hl[tid - 256] = rrc[tid - 256];

    // ---- z rows: bias + sum of split-K partial panels (or prereduced fallback) ----
    float va, vb;
    if (nsp) {
        va = benc[tid]; vb = va;
        const float* zp0 = z + (size_t)b0 * 512;
        const float* zp1 = z + (size_t)b1 * 512;
        for (int s = 0; s < nsp; ++s) {
            va += zp0[(size_t)s * 524288 + tid];
            vb += zp1[(size_t)s * 524288 + tid];
        }
    } else {
        va = z[(size_t)b0 * 512 + tid];
        vb = z[(size_t)b1 * 512 + tid];
    }
    __syncthreads();

    // ---- gcs: carrier folded into RRC taps ----
    if (tid < LENRRC_) {
        int neg = (16 - (tid & 15)) & 15;                // (-d) & 15
        gcs[tid] = make_float2(hl[tid] * csl[neg], hl[tid] * ssl[neg]);
    }

    // ---- power norm (single pass: S, Q; ddof=1), both rows; fold (-1)^q into zl ----
    {
        float S0 = wave_sum(va), Q0 = wave_sum(va * va);
        float S1 = wave_sum(vb), Q1 = wave_sum(vb * vb);
        if (lane == 0) { red[0][wv] = S0; red2[0][wv] = Q0; red[1][wv] = S1; red2[1][wv] = Q1; }
    }
    __syncthreads();
    {
        float S0 = 0.f, Q0 = 0.f, S1 = 0.f, Q1 = 0.f;
        #pragma unroll
        for (int w = 0; w < 8; ++w) {
            S0 += red[0][w]; Q0 += red2[0][w];
            S1 += red[1][w]; Q1 += red2[1][w];
        }
        float m0 = S0 * (1.f / 512.f), m1 = S1 * (1.f / 512.f);
        float i0 = 1.f / (sqrtf((Q0 - S0 * m0) * (1.f / 511.f)) + 1e-8f);
        float i1 = 1.f / (sqrtf((Q1 - S1 * m1) * (1.f / 511.f)) + 1e-8f);
        float sg = ((tid >> 1) & 1) ? -1.f : 1.f;        // (-1)^q, q = tid>>1
        zl[0][tid] = (va - m0) * i0 * sg;
        zl[1][tid] = (vb - m1) * i1 * sg;
    }
    __syncthreads();

    // ---- P12: fused DFT32+IDFT64+CP. Each thread: 1 odd + 1 even output of its row ----
    {
        int r = tid >> 8, t = tid & 255;
        int s = t >> 5, j = t & 31;
        int base = s * 80;                               // data at [base+32 .. base+95]
        const float2* zs = (const float2*)&zl[r][s * 64];
        // odd n = 2j+1: dense cot sum
        int n = 2 * j + 1;
        float Zr = 0.f, Zi = 0.f, Tr = 0.f, Ti = 0.f;
        #pragma unroll 4
        for (int q = 0; q < 32; ++q) {
            float2 a = zs[q];
            float w = ct[(n - 2 * q) & 63];
            Zr += a.x; Zi += a.y;
            Tr += a.x * w; Ti += a.y * w;
        }
        {
            float2 cw = cs64[(n * sloc) & 63];
            float Ar = Zr - Ti, Ai = Zi + Tr;            // Z + i*T
            float dr = S2048 * (Ar * cw.x - Ai * cw.y);
            float di = S2048 * (Ai * cw.x + Ar * cw.y);
            trti[r][base + 32 + n] = make_float2(dr, di);
            if (n >= 48) trti[r][base + n - 32] = make_float2(dr, di);   // CP
        }
        // even n = 2j: trivial (interpolation identity)
        {
            int n2 = 2 * j;
            float2 a = zs[j];
            float2 cw = cs64[(n2 * sloc) & 63];
            const float RS2 = 0.7071067811865476f;       // 1/sqrt2
            float dr = RS2 * (a.x * cw.x - a.y * cw.y);
            float di = RS2 * (a.y * cw.x + a.x * cw.y);
            trti[r][base + 32 + n2] = make_float2(dr, di);
            if (n2 >= 48) trti[r][base + n2 - 32] = make_float2(dr, di); // CP
        }
    }
    __syncthreads();

    // ---- P3: upsample x8 + RRC polyphase + carrier, task=(a,g), both rows share hl ----
    float ss0 = 0.f, ss1 = 0.f;
    for (int tsk = tid; tsk < 1312; tsk += 512) {
        int a = tsk >> 1, g = tsk & 1;
        float ar0[4] = {}, ai0[4] = {}, ar1[4] = {}, ai1[4] = {};
        #pragma unroll 4
        for (int d = 0; d < 16; ++d) {
            float2 t0 = trti[0][16 + a - d];             // zero-padded: no bounds check
            float2 t1 = trti[1][16 + a - d];
            #pragma unroll
            for (int r = 0; r < 4; ++r) {
                float h = hl[g * 4 + r + 8 * d];
                ar0[r] += t0.x * h; ai0[r] += t0.y * h;
                ar1[r] += t1.x * h; ai1[r] += t1.y * h;
            }
        }
        if (g == 0) {                                    // d=16, tap 128, r=0 only
            float2 t0 = trti[0][a], t1 = trti[1][a];
            float h = hl[128];
            ar0[0] += t0.x * h; ai0[0] += t0.y * h;
            ar1[0] += t1.x * h; ai1[0] += t1.y * h;
        }
        int cb = (a & 1) * 8;
        #pragma unroll
        for (int r = 0; r < 4; ++r) {
            int rr = g * 4 + r;
            float cv = csl[cb + rr], sv = ssl[cb + rr];
            float v0 = ar0[r] * cv - ai0[r] * sv;
            float v1 = ar1[r] * cv - ai1[r] * sv;
            dxr[0][SWZ(a * 8 + rr)] = v0;
            dxr[1][SWZ(a * 8 + rr)] = v1;
            ss0 += v0 * v0; ss1 += v1 * v1;
        }
    }
    ss0 = wave_sum(ss0); ss1 = wave_sum(ss1);
    if (lane == 0) { red[0][wv] = ss0; red[1][wv] = ss1; }
    __syncthreads();
    float thr0, thr1;
    {
        float S0 = 0.f, S1 = 0.f;
        #pragma unroll
        for (int w = 0; w < 8; ++w) { S0 += red[0][w]; S1 += red[1][w]; }
        thr0 = 1.2f * sqrtf(S0 / (float)L1_);
        thr1 = 1.2f * sqrtf(S1 / (float)L1_);
    }
    __syncthreads();

    // ---- P5: clip + PAPR window stats + AWGN (in place), both rows ----
    float pm0 = 0.f, ps0 = 0.f, pm1 = 0.f, ps1 = 0.f;
    {
        const float4* ag0 = (const float4*)&awgn[(size_t)b0 * L1_];
        const float4* ag1 = (const float4*)&awgn[(size_t)b1 * L1_];
        for (int ii = tid; ii < 1312; ii += 512) {       // 1312*4 = 5248
            float4 a0 = ag0[ii], a1 = ag1[ii];
            int i = ii * 4;
            #pragma unroll
            for (int e = 0; e < 4; ++e) {
                int idx = i + e;
                bool win = (idx >= TSTART_ && idx < TSTART_ + NWIN_);
                float aw0 = (e == 0) ? a0.x : (e == 1) ? a0.y : (e == 2) ? a0.z : a0.w;
                float aw1 = (e == 0) ? a1.x : (e == 1) ? a1.y : (e == 2) ? a1.z : a1.w;
                {
                    float x = dxr[0][SWZ(idx)];
                    float ax = fabsf(x);
                    float over = fmaxf(ax - thr0, 0.f);
                    float y = (1.f - over / (ax + 1e-8f)) * x;
                    if (win) { float p = y * y; ps0 += p; pm0 = fmaxf(pm0, p); }
                    dxr[0][SWZ(idx)] = y + aw0;
                }
                {
                    float x = dxr[1][SWZ(idx)];
                    float ax = fabsf(x);
                    float over = fmaxf(ax - thr1, 0.f);
                    float y = (1.f - over / (ax + 1e-8f)) * x;
                    if (win) { float p = y * y; ps1 += p; pm1 = fmaxf(pm1, p); }
                    dxr[1][SWZ(idx)] = y + aw1;
                }
            }
        }
    }
    ps0 = wave_sum(ps0); pm0 = wave_max(pm0);
    ps1 = wave_sum(ps1); pm1 = wave_max(pm1);
    if (lane == 0) { red[0][wv] = ps0; red2[0][wv] = pm0; red[1][wv] = ps1; red2[1][wv] = pm1; }
    __syncthreads();
    if (tid == 0) {
        float s0 = 0.f, m0 = 0.f, s1 = 0.f, m1 = 0.f;
        #pragma unroll
        for (int w = 0; w < 8; ++w) {
            s0 += red[0][w]; m0 = fmaxf(m0, red2[0][w]);
            s1 += red[1][w]; m1 = fmaxf(m1, red2[1][w]);
        }
        float p0 = 10.f * log10f(m0 / (s0 / (float)NWIN_));
        float p1 = 10.f * log10f(m1 / (s1 / (float)NWIN_));
        papr[b0] = p0; out_papr[b0] = p0;
        papr[b1] = p1; out_papr[b1] = p1;
    }
    __syncthreads();     // all P5 dxr writes visible before P6

    // ---- P6: matched RRC filter -> w~[n] = w[n]*conj(W[n*sloc]) into trti[s*64+n] ----
    {
        int s = wv, n = lane;                            // 8 waves x 64 outputs, both rows
        int T0 = s * 80 + n + 32;                        // Nf/8
        int base = 9 * T0;                               // SWZ(Nf)
        float ar0 = 0.f, ai0 = 0.f, ar1 = 0.f, ai1 = 0.f;
        int db = 0;
        #pragma unroll 4
        for (int e = 0; e < 16; ++e) {
            float4 g01 = *(const float4*)&gcs[db];       // gcs[db], gcs[db+1]
            float4 g23 = *(const float4*)&gcs[db + 2];
            float4 g45 = *(const float4*)&gcs[db + 4];
            float4 g67 = *(const float4*)&gcs[db + 6];
            float gx[8] = { g01.x, g01.z, g23.x, g23.z, g45.x, g45.z, g67.x, g67.z };
            float gy[8] = { g01.y, g01.w, g23.y, g23.w, g45.y, g45.w, g67.y, g67.w };
            #pragma unroll
            for (int u = 0; u < 8; ++u) {
                int off = (u == 0) ? 0 : (u + 1);
                float v0 = dxr[0][base - off];
                float v1 = dxr[1][base - off];
                ar0 += v0 * gx[u]; ai0 += v0 * gy[u];
                ar1 += v1 * gx[u]; ai1 += v1 * gy[u];
            }
            base -= 9; db += 8;
        }
        {
            float2 g = gcs[128];
            float v0 = dxr[0][base], v1 = dxr[1][base];
            ar0 += v0 * g.x; ai0 += v0 * g.y;
            ar1 += v1 * g.x; ai1 += v1 * g.y;
        }
        bool odd = (n & 1);
        float wr0 = odd ? -ar0 : ar0, wi0 = odd ? ai0 : -ai0;
        float wr1 = odd ? -ar1 : ar1, wi1 = odd ? ai1 : -ai1;
        float2 cw = cs64[(n * sloc) & 63];               // w~ = w * conj(W)
        trti[0][s * 64 + n] = make_float2(wr0 * cw.x + wi0 * cw.y, wi0 * cw.x - wr0 * cw.y);
        trti[1][s * 64 + n] = make_float2(wr1 * cw.x + wi1 * cw.y, wi1 * cw.x - wr1 * cw.y);
    }
    __syncthreads();

    // ---- P78: fused DFT64-band-select + IDFT32 via cot identity -> y5b bf16 ----
    {
        int r = tid >> 8, t = tid & 255;
        int s = t >> 5, q = t & 31;
        const float2* wt = &trti[r][s * 64];
        float Wr = 0.f, Wi = 0.f, Ur = 0.f, Ui = 0.f;
        #pragma unroll 4
        for (int u = 0; u < 32; ++u) {
            float2 a = wt[2 * u + 1];
            float w = ct[(2 * q - 2 * u - 1) & 63];
            Wr += a.x; Wi += a.y;
            Ur += a.x * w; Ui += a.y * w;
        }
        float2 e = wt[2 * q];
        float sgn = (q & 1) ? -S2048 : S2048;            // (-1)^q / sqrt2048
        float yr = sgn * (32.f * e.x + Wr - Ui);
        float yi = sgn * (32.f * e.y + Wi + Ur);
        ushort2 h; h.x = bf16_rne(yr); h.y = bf16_rne(yi);
        *(ushort2*)&y5b[(size_t)(b0 + r) * 512 + (s * 32 + q) * 2] = h;
    }
}

extern "C" void kernel_launch(void* const* d_in, const int* in_sizes, int n_in,
                              void* d_out, int out_size, void* d_ws, size_t ws_size,
                              hipStream_t stream) {
    const float* x    = (const float*)d_in[0];
    const float* Wenc = (const float*)d_in[1];
    const float* benc = (const float*)d_in[2];
    const float* Wdec = (const float*)d_in[3];
    const float* bdec = (const float*)d_in[4];
    const float* rrc  = (const float*)d_in[5];
    const float* awgn = (const float*)d_in[6];
    const int* sloc   = (const int*)d_in[7];
    float* out = (float*)d_out;

    char* wsb = (char*)d_ws;
    ushort* w1t  = (ushort*)wsb;                     wsb += (size_t)512 * 3072 * 2;
    ushort* w2t  = (ushort*)wsb;                     wsb += (size_t)3072 * 512 * 2;
    ushort* y5b  = (ushort*)wsb;                     wsb += (size_t)1024 * 512 * 2;
    float*  papr = (float*)wsb;                      wsb += 1024 * 4;
    float*  zbuf = (float*)wsb;                      // partial: 8 x 1024x512 f32 (16.8 MB)
                                                     // fallback: 1024x512 f32 (2.1 MB)
    size_t head = (size_t)((char*)zbuf - (char*)d_ws);
    int partial = (ws_size >= head + (size_t)8 * 1024 * 512 * 4) ? 1 : 0;

    float* out_papr = out + (size_t)1024 * 3072;
    float* out_loss = out_papr + 1024;

    pack_k<<<partial ? 768 : 2816, 256, 0, stream>>>(Wenc, Wdec, benc, w1t, w2t, zbuf);
    gemm1_k<<<dim3(4, 16, 8), 256, 0, stream>>>(x, w1t, zbuf, 1024, 512, 3072, partial);
    mega_k<<<512, 512, 0, stream>>>(zbuf, benc, rrc, awgn, sloc, y5b, papr, out_papr,
                                    partial ? 8 : 0);
    gemm2_k<<<dim3(48, 16, 1), 256, 0, stream>>>(y5b, w2t, bdec, papr, out, out_loss, 1024, 3072, 512);
}